// Round 9
// baseline (218.425 us; speedup 1.0000x reference)
//
#include <hip/hip_runtime.h>
#include <hip/hip_bf16.h>
#include <stdint.h>

#define EMBED 1024
#define NH 16
#define HD 64
#define BATCH 2
#define QLEN 2048
#define CLEN 2048

typedef short short8 __attribute__((ext_vector_type(8)));
typedef unsigned short ushort8v __attribute__((ext_vector_type(8)));
typedef float f32x4 __attribute__((ext_vector_type(4)));
typedef float f32x16 __attribute__((ext_vector_type(16)));
typedef uint32_t u32x4 __attribute__((ext_vector_type(4)));

// softmax scale folded into Q projection: 1/sqrt(64) * log2(e)
#define QSCALE 0.18033688f

__device__ __forceinline__ void async_load16(const void* g, void* l) {
    __builtin_amdgcn_global_load_lds((const __attribute__((address_space(1))) void*)g,
                                     (__attribute__((address_space(3))) void*)l, 16, 0, 0);
}

__device__ __forceinline__ uint32_t pack2(float a, float b) {
    float2 f{a, b};
    __hip_bfloat162 t = __float22bfloat162_rn(f);
    uint32_t u;
    __builtin_memcpy(&u, &t, 4);
    return u;
}

// ---------------- prep: activations cvt (y=0,1) + weight transposes (y=2..5) ----------------
__global__ void prep(const float* __restrict__ query, const float* __restrict__ context,
                     __hip_bfloat16* __restrict__ qbf, __hip_bfloat16* __restrict__ cbf,
                     const float* __restrict__ W0, const float* __restrict__ W1,
                     const float* __restrict__ W2, const float* __restrict__ W3,
                     __hip_bfloat16* __restrict__ T0, __hip_bfloat16* __restrict__ T1,
                     __hip_bfloat16* __restrict__ T2, __hip_bfloat16* __restrict__ T3) {
    const int y = blockIdx.y;
    const int tid = threadIdx.x;
    if (y < 2) {
        const float* src = y ? context : query;
        __hip_bfloat16* dst = y ? cbf : qbf;
#pragma unroll
        for (int k = 0; k < 4; k++) {
            const int i = (blockIdx.x * 1024 + k * 256 + tid) * 4;
            float4 v = *(const float4*)(src + i);
            __hip_bfloat16 h[4];
            h[0] = __float2bfloat16(v.x);
            h[1] = __float2bfloat16(v.y);
            h[2] = __float2bfloat16(v.z);
            h[3] = __float2bfloat16(v.w);
            *(ushort4*)(dst + i) = *(const ushort4*)h;
        }
    } else {
        const int z = y - 2;
        const float* W = z == 0 ? W0 : z == 1 ? W1 : z == 2 ? W2 : W3;
        __hip_bfloat16* Wt = z == 0 ? T0 : z == 1 ? T1 : z == 2 ? T2 : T3;
        __shared__ float t[32][33];
        const int tx = tid & 31, ty = tid >> 5;
        const int n0 = (blockIdx.x & 31) * 32, k0 = (blockIdx.x >> 5) * 32;
#pragma unroll
        for (int r = 0; r < 4; r++)
            t[ty * 4 + r][tx] = W[(size_t)(k0 + ty * 4 + r) * EMBED + n0 + tx];
        __syncthreads();
#pragma unroll
        for (int r = 0; r < 4; r++)
            Wt[(size_t)(n0 + ty * 4 + r) * EMBED + k0 + tx] = __float2bfloat16(t[tx][ty * 4 + r]);
    }
}

// ---------------- 128x128 GEMM accumulate body (BK=32, B^T layout, K=1024) ----------------
__device__ __forceinline__ void gemm128_acc(
    const __hip_bfloat16* __restrict__ A, const __hip_bfloat16* __restrict__ Bt,
    int m0, int n0, __hip_bfloat16* As, __hip_bfloat16* Bs, f32x4 acc[4][4]) {
    const int K = EMBED;
    const int tid = threadIdx.x;
    const int wave = __builtin_amdgcn_readfirstlane(tid >> 6);
    const int lane = tid & 63, l15 = lane & 15, quad = lane >> 4;
    const int wm = (wave >> 1) * 64, wn = (wave & 1) * 64;
    const int srow = tid >> 2, sseg = (tid & 3) * 8;
    for (int k0 = 0; k0 < K; k0 += 32) {
        __syncthreads();
#pragma unroll
        for (int s = 0; s < 2; s++) {
            async_load16(A + (size_t)(m0 + s * 64 + srow) * K + k0 + sseg,
                         As + (size_t)(s * 256 + wave * 64) * 8);
            async_load16(Bt + (size_t)(n0 + s * 64 + srow) * K + k0 + sseg,
                         Bs + (size_t)(s * 256 + wave * 64) * 8);
        }
        __syncthreads();
        short8 af[4], bf[4];
#pragma unroll
        for (int t = 0; t < 4; t++) {
            af[t] = *(const short8*)(As + (wm + t * 16 + l15) * 32 + quad * 8);
            bf[t] = *(const short8*)(Bs + (wn + t * 16 + l15) * 32 + quad * 8);
        }
#pragma unroll
        for (int mt = 0; mt < 4; mt++)
#pragma unroll
            for (int nt = 0; nt < 4; nt++)
                acc[mt][nt] = __builtin_amdgcn_mfma_f32_16x16x32_bf16(af[mt], bf[nt], acc[mt][nt], 0, 0, 0);
    }
}

// ---------------- fused Q + K + V projections (V^T via LDS bounce, Q pre-scaled) ----------------
__global__ __launch_bounds__(256, 3) void proj128(
    const __hip_bfloat16* __restrict__ qbf, const __hip_bfloat16* __restrict__ cbf,
    const __hip_bfloat16* __restrict__ Wqt, const __hip_bfloat16* __restrict__ Wkvt,
    const float* __restrict__ bq, const float* __restrict__ bk, const float* __restrict__ bv,
    __hip_bfloat16* __restrict__ Qp, __hip_bfloat16* __restrict__ Kp, __hip_bfloat16* __restrict__ Vtr) {
    __shared__ __hip_bfloat16 smem[8704];  // As(4096) + Bs(4096); reused as T[64][136]
    __hip_bfloat16* As = smem;
    __hip_bfloat16* Bs = smem + 4096;
    const int j = blockIdx.x;
    const int blk = (j & 7) * 96 + (j >> 3);   // XCD swizzle
    const __hip_bfloat16 *A, *Bt;
    int m0, n0;
    if (blk < 256) {
        A = qbf; Bt = Wqt; m0 = (blk >> 3) * 128; n0 = (blk & 7) * 128;
    } else {
        const int f = blk - 256;
        A = cbf; Bt = Wkvt; m0 = (f >> 4) * 128; n0 = (f & 15) * 128;
    }
    f32x4 acc[4][4] = {};
    gemm128_acc(A, Bt, m0, n0, As, Bs, acc);

    const int tid = threadIdx.x;
    const int wave = __builtin_amdgcn_readfirstlane(tid >> 6);
    const int lane = tid & 63, l15 = lane & 15, quad = lane >> 4;
    const int wm = (wave >> 1) * 64, wn = (wave & 1) * 64;

    if (blk >= 256 && n0 >= 1024) {
        // V block: transpose 128x128 via LDS (two 64-col halves), coalesced writes
        const int cb = n0 - 1024;
        const int b2 = m0 >> 11;
        const int tokb = m0 & 2047;
        __hip_bfloat16* T = smem;  // 64 x 136 (pad keeps writes ~conflict-free, 8B-aligned)
#pragma unroll
        for (int hh = 0; hh < 2; hh++) {
            __syncthreads();
            if ((wn >> 6) == hh) {
#pragma unroll
                for (int nt = 0; nt < 4; nt++) {
                    const int cn = nt * 16 + l15;
                    const float bvv = bv[cb + hh * 64 + cn];
#pragma unroll
                    for (int mt = 0; mt < 4; mt++) {
                        const int m = wm + mt * 16 + quad * 4;
                        __hip_bfloat16 vb[4];
#pragma unroll
                        for (int r = 0; r < 4; r++) vb[r] = __float2bfloat16(acc[mt][nt][r] + bvv);
                        *(ushort4*)(T + cn * 136 + m) = *(const ushort4*)vb;
                    }
                }
            }
            __syncthreads();
            const int r = tid >> 2;
            const int seg = (tid & 3) * 32;
            unsigned short* dst = (unsigned short*)Vtr +
                (size_t)(b2 * 1024 + cb + hh * 64 + r) * CLEN + tokb + seg;
            const unsigned short* srcp = (const unsigned short*)(T + r * 136 + seg);
#pragma unroll
            for (int u = 0; u < 4; u++)
                *(ushort8v*)(dst + u * 8) = *(const ushort8v*)(srcp + u * 8);
        }
    } else {
        const bool isQ = (blk < 256);
        const float* bias = isQ ? bq : bk;
        __hip_bfloat16* C = isQ ? Qp : Kp;
        const float sc = isQ ? QSCALE : 1.0f;
#pragma unroll
        for (int mt = 0; mt < 4; mt++) {
#pragma unroll
            for (int nt = 0; nt < 4; nt++) {
                const int c = n0 + wn + nt * 16 + l15;
                const float bvv = bias[c];
                const int r0 = m0 + wm + mt * 16 + quad * 4;
#pragma unroll
                for (int r = 0; r < 4; r++)
                    C[(size_t)(r0 + r) * 1024 + c] = __float2bfloat16((acc[mt][nt][r] + bvv) * sc);
            }
        }
    }
}

// ---------------- output projection: 64x128 tiles, fp32 out, XCD swizzle ----------------
__global__ __launch_bounds__(256, 4) void oproj(
    const __hip_bfloat16* __restrict__ A, const __hip_bfloat16* __restrict__ Bt,
    const float* __restrict__ bias, float* __restrict__ C) {
    __shared__ __hip_bfloat16 As[64 * 32];
    __shared__ __hip_bfloat16 Bs[128 * 32];
    const int K = EMBED, N = EMBED;
    const int j = blockIdx.x;
    const int L = (j & 7) * 64 + (j >> 3);
    const int m0 = (L >> 3) * 64, n0 = (L & 7) * 128;
    const int tid = threadIdx.x;
    const int wave = __builtin_amdgcn_readfirstlane(tid >> 6);
    const int lane = tid & 63, l15 = lane & 15, quad = lane >> 4;
    const int wm = (wave & 1) * 32, wn = (wave >> 1) * 64;
    const int srow = tid >> 2, sseg = (tid & 3) * 8;
    f32x4 acc[2][4] = {};
    for (int k0 = 0; k0 < K; k0 += 32) {
        __syncthreads();
        async_load16(A + (size_t)(m0 + srow) * K + k0 + sseg, As + (size_t)(wave * 64) * 8);
#pragma unroll
        for (int s = 0; s < 2; s++)
            async_load16(Bt + (size_t)(n0 + s * 64 + srow) * K + k0 + sseg,
                         Bs + (size_t)(s * 256 + wave * 64) * 8);
        __syncthreads();
        short8 af[2], bf[4];
#pragma unroll
        for (int t = 0; t < 2; t++)
            af[t] = *(const short8*)(As + (wm + t * 16 + l15) * 32 + quad * 8);
#pragma unroll
        for (int t = 0; t < 4; t++)
            bf[t] = *(const short8*)(Bs + (wn + t * 16 + l15) * 32 + quad * 8);
#pragma unroll
        for (int mt = 0; mt < 2; mt++)
#pragma unroll
            for (int nt = 0; nt < 4; nt++)
                acc[mt][nt] = __builtin_amdgcn_mfma_f32_16x16x32_bf16(af[mt], bf[nt], acc[mt][nt], 0, 0, 0);
    }
#pragma unroll
    for (int mt = 0; mt < 2; mt++) {
#pragma unroll
        for (int nt = 0; nt < 4; nt++) {
            const int c = n0 + wn + nt * 16 + l15;
            const float bvv = bias[c];
            const int r0 = m0 + wm + mt * 16 + quad * 4;
#pragma unroll
            for (int r = 0; r < 4; r++)
                C[(size_t)(r0 + r) * N + c] = acc[mt][nt][r] + bvv;
        }
    }
}

// ---------------- flash attention: 32x32x16 MFMA, S^T form, c-split x2 ----------------
// Conflict-free LDS swizzle: phys granule = logical ^ (row&7) ^ (row>>3).
// lsum accumulated on the matrix pipe via ones-row MFMA.
__global__ __launch_bounds__(256, 4) void flash_attn(
    const __hip_bfloat16* __restrict__ Q, const __hip_bfloat16* __restrict__ K,
    const __hip_bfloat16* __restrict__ Vt, __hip_bfloat16* __restrict__ O) {
    __shared__ __hip_bfloat16 Ks[2][64 * 64];
    __shared__ __hip_bfloat16 Vs[2][64 * 64];
    const int tid = threadIdx.x;
    const int wave = __builtin_amdgcn_readfirstlane(tid >> 6);
    const int wq = wave & 1, wc = wave >> 1;
    const int lane = tid & 63, l31 = lane & 31, hbit = lane >> 5;
    const int j = blockIdx.x;
    const int L = (j & 7) * 128 + (j >> 3);  // XCD swizzle: 4 heads per XCD
    const int hy = L >> 5;
    const int b = hy >> 4, h = hy & 15;
    const int q0 = (L & 31) * 64;
    const size_t kbase = (size_t)b * CLEN * EMBED + (size_t)h * HD;
    const size_t vtbase = (size_t)((b * NH + h) * HD) * CLEN;
    const int srow8 = lane >> 3;               // 0..7
    const int sgb = (lane & 7) ^ srow8;        // swizzle base; per-issue: sgb ^ i
    __hip_bfloat16* stK = Ks[wc];
    __hip_bfloat16* stV = Vs[wc];

    const __hip_bfloat16* qptr =
        Q + (size_t)(b * QLEN + q0 + wq * 32 + l31) * EMBED + h * HD + hbit * 8;
    short8 qf[4];
#pragma unroll
    for (int t = 0; t < 4; t++) qf[t] = *(const short8*)(qptr + t * 16);

    short8 ones;
#pragma unroll
    for (int t = 0; t < 8; t++) ones[t] = (short)0x3F80;  // bf16 1.0

    f32x16 o[2] = {};
    f32x16 o_sum = {};
    const int cbase = wc * (CLEN / 2);

    for (int t = 0; t < 16; ++t) {
        const int c0 = cbase + t * 64;
        __syncthreads();
        // wave-uniform LDS dest; lane L -> row i*8+(L>>3), phys granule L&7;
        // source col granule = (L&7)^(L>>3)^i so that phys = logical^(row&7)^(row>>3)
        if (wq == 0) {
#pragma unroll
            for (int i = 0; i < 8; i++)
                async_load16(K + kbase + (size_t)(c0 + i * 8 + srow8) * EMBED + (sgb ^ i) * 8,
                             stK + i * 512);
        } else {
#pragma unroll
            for (int i = 0; i < 8; i++)
                async_load16(Vt + vtbase + (size_t)(i * 8 + srow8) * CLEN + c0 + (sgb ^ i) * 8,
                             stV + i * 512);
        }
        __syncthreads();

#pragma unroll
        for (int mc = 0; mc < 2; mc++) {
            const int row = mc * 32 + l31;
            const int rsw = (row & 7) ^ (row >> 3);
            const __hip_bfloat16* kr = stK + row * 64;
            f32x16 s = {};
#pragma unroll
            for (int kc = 0; kc < 4; kc++) {
                short8 kf = *(const short8*)(kr + ((2 * kc + hbit) ^ rsw) * 8);
                s = __builtin_amdgcn_mfma_f32_32x32x16_bf16(kf, qf[kc], s, 0, 0, 0);
            }
            uint32_t dw[8];
#pragma unroll
            for (int i = 0; i < 8; i++) {
                const float p0 = __builtin_amdgcn_exp2f(s[2 * i]);
                const float p1 = __builtin_amdgcn_exp2f(s[2 * i + 1]);
                dw[i] = pack2(p0, p1);
            }
#pragma unroll
            for (int tp = 0; tp < 2; tp++) {
                u32x4 fb;
#if __has_builtin(__builtin_amdgcn_permlane32_swap)
                {
                    auto s02 = __builtin_amdgcn_permlane32_swap(dw[4 * tp + 0], dw[4 * tp + 2], false, false);
                    auto s13 = __builtin_amdgcn_permlane32_swap(dw[4 * tp + 1], dw[4 * tp + 3], false, false);
                    fb[0] = s02[0];
                    fb[1] = s13[0];
                    fb[2] = s02[1];
                    fb[3] = s13[1];
                }
#else
                {
                    const uint32_t a0 = hbit ? dw[4 * tp + 2] : dw[4 * tp + 0];
                    const uint32_t a1 = hbit ? dw[4 * tp + 3] : dw[4 * tp + 1];
                    const uint32_t b0 = hbit ? dw[4 * tp + 0] : dw[4 * tp + 2];
                    const uint32_t b1 = hbit ? dw[4 * tp + 1] : dw[4 * tp + 3];
                    const uint32_t x0 = (uint32_t)__shfl_xor((int)b0, 32);
                    const uint32_t x1 = (uint32_t)__shfl_xor((int)b1, 32);
                    fb[0] = hbit ? x0 : a0;
                    fb[1] = hbit ? x1 : a1;
                    fb[2] = hbit ? a0 : x0;
                    fb[3] = hbit ? a1 : x1;
                }
#endif
                const short8 pfr = __builtin_bit_cast(short8, fb);
                const int kc2 = mc * 2 + tp;
#pragma unroll
                for (int dm = 0; dm < 2; dm++) {
                    const int vrow = dm * 32 + l31;
                    const int vsw = (vrow & 7) ^ (vrow >> 3);
                    short8 vf = *(const short8*)(stV + vrow * 64 + ((2 * kc2 + hbit) ^ vsw) * 8);
                    o[dm] = __builtin_amdgcn_mfma_f32_32x32x16_bf16(vf, pfr, o[dm], 0, 0, 0);
                }
                o_sum = __builtin_amdgcn_mfma_f32_32x32x16_bf16(ones, pfr, o_sum, 0, 0, 0);
            }
        }
    }
    float lsum = o_sum[0];  // row-independent: sum_c exp for q=l31 over this wave's c-half

    // ---- combine c-halves (additive), then normalize & store ----
    __syncthreads();
    float4* scr4 = (float4*)&Ks[0][0];
    float* scrl = (float*)&Vs[0][0];
    if (wc == 1) {
#pragma unroll
        for (int i = 0; i < 8; i++) {
            float4 c4;
            c4.x = o[i >> 2][(i & 3) * 4 + 0];
            c4.y = o[i >> 2][(i & 3) * 4 + 1];
            c4.z = o[i >> 2][(i & 3) * 4 + 2];
            c4.w = o[i >> 2][(i & 3) * 4 + 3];
            scr4[i * 128 + wq * 64 + lane] = c4;
        }
        scrl[wq * 64 + lane] = lsum;
    }
    __syncthreads();
    if (wc == 0) {
        lsum += scrl[wq * 64 + lane];
#pragma unroll
        for (int i = 0; i < 8; i++) {
            float4 p = scr4[i * 128 + wq * 64 + lane];
            o[i >> 2][(i & 3) * 4 + 0] += p.x;
            o[i >> 2][(i & 3) * 4 + 1] += p.y;
            o[i >> 2][(i & 3) * 4 + 2] += p.z;
            o[i >> 2][(i & 3) * 4 + 3] += p.w;
        }
        const float inv = 1.0f / lsum;
        const int q = q0 + wq * 32 + l31;
        __hip_bfloat16* orow = O + (size_t)(b * QLEN + q) * EMBED + h * HD;
#pragma unroll
        for (int dm = 0; dm < 2; dm++) {
#pragma unroll
            for (int g = 0; g < 4; g++) {
                __hip_bfloat16 ob[4];
#pragma unroll
                for (int r = 0; r < 4; r++) ob[r] = __float2bfloat16(o[dm][g * 4 + r] * inv);
                *(ushort4*)(orow + dm * 32 + hbit * 4 + g * 8) = *(const ushort4*)ob;
            }
        }
    }
}

extern "C" void kernel_launch(void* const* d_in, const int* in_sizes, int n_in,
                              void* d_out, int out_size, void* d_ws, size_t ws_size,
                              hipStream_t stream) {
    const float* query = (const float*)d_in[0];
    const float* context = (const float*)d_in[1];
    const float* Wq = (const float*)d_in[2];
    const float* bq = (const float*)d_in[3];
    const float* Wk = (const float*)d_in[4];
    const float* bk = (const float*)d_in[5];
    const float* Wv = (const float*)d_in[6];
    const float* bv = (const float*)d_in[7];
    const float* Wo = (const float*)d_in[8];
    const float* bo = (const float*)d_in[9];
    float* out = (float*)d_out;

    const int NTOK = BATCH * QLEN;   // 4096
    const int NACT = NTOK * EMBED;   // 4,194,304
    const int NW = EMBED * EMBED;    // 1,048,576

    __hip_bfloat16* qbf = (__hip_bfloat16*)d_ws;
    __hip_bfloat16* cbf = qbf + NACT;
    __hip_bfloat16* Wqt = cbf + NACT;
    __hip_bfloat16* Wkt = Wqt + NW;   // Wkt,Wvt contiguous = fused 2048x1024 B^T
    __hip_bfloat16* Wvt = Wkt + NW;
    __hip_bfloat16* Wot = Wvt + NW;
    __hip_bfloat16* Qp = Wot + NW;
    __hip_bfloat16* Kp = Qp + NACT;
    __hip_bfloat16* Vtr = Kp + NACT;   // V^T ((b*16+h)*64+d) x 2048
    __hip_bfloat16* att = Vtr + NACT;  // attended output

    prep<<<dim3(1024, 6), 256, 0, stream>>>(query, context, qbf, cbf,
                                            Wq, Wk, Wv, Wo, Wqt, Wkt, Wvt, Wot);

    proj128<<<768, 256, 0, stream>>>(qbf, cbf, Wqt, Wkt, bq, bk, bv, Qp, Kp, Vtr);

    flash_attn<<<1024, 256, 0, stream>>>(Qp, Kp, Vtr, att);

    oproj<<<512, 256, 0, stream>>>(att, Wot, bo, out);
}

// Round 10
// 203.696 us; speedup vs baseline: 1.0723x; 1.0723x over previous
//
#include <hip/hip_runtime.h>
#include <hip/hip_bf16.h>
#include <stdint.h>

#define EMBED 1024
#define NH 16
#define HD 64
#define BATCH 2
#define QLEN 2048
#define CLEN 2048

typedef short short8 __attribute__((ext_vector_type(8)));
typedef unsigned short ushort8v __attribute__((ext_vector_type(8)));
typedef float f32x4 __attribute__((ext_vector_type(4)));
typedef float f32x16 __attribute__((ext_vector_type(16)));
typedef uint32_t u32x4 __attribute__((ext_vector_type(4)));

// softmax scale folded into Q projection: 1/sqrt(64) * log2(e)
#define QSCALE 0.18033688f

__device__ __forceinline__ void async_load16(const void* g, void* l) {
    __builtin_amdgcn_global_load_lds((const __attribute__((address_space(1))) void*)g,
                                     (__attribute__((address_space(3))) void*)l, 16, 0, 0);
}

__device__ __forceinline__ uint32_t pack2(float a, float b) {
    float2 f{a, b};
    __hip_bfloat162 t = __float22bfloat162_rn(f);
    uint32_t u;
    __builtin_memcpy(&u, &t, 4);
    return u;
}

// ---------------- prep: activations cvt (y=0,1) + weight transposes (y=2..5) ----------------
__global__ void prep(const float* __restrict__ query, const float* __restrict__ context,
                     __hip_bfloat16* __restrict__ qbf, __hip_bfloat16* __restrict__ cbf,
                     const float* __restrict__ W0, const float* __restrict__ W1,
                     const float* __restrict__ W2, const float* __restrict__ W3,
                     __hip_bfloat16* __restrict__ T0, __hip_bfloat16* __restrict__ T1,
                     __hip_bfloat16* __restrict__ T2, __hip_bfloat16* __restrict__ T3) {
    const int y = blockIdx.y;
    const int tid = threadIdx.x;
    if (y < 2) {
        const float* src = y ? context : query;
        __hip_bfloat16* dst = y ? cbf : qbf;
#pragma unroll
        for (int k = 0; k < 4; k++) {
            const int i = (blockIdx.x * 1024 + k * 256 + tid) * 4;
            float4 v = *(const float4*)(src + i);
            __hip_bfloat16 h[4];
            h[0] = __float2bfloat16(v.x);
            h[1] = __float2bfloat16(v.y);
            h[2] = __float2bfloat16(v.z);
            h[3] = __float2bfloat16(v.w);
            *(ushort4*)(dst + i) = *(const ushort4*)h;
        }
    } else {
        const int z = y - 2;
        const float* W = z == 0 ? W0 : z == 1 ? W1 : z == 2 ? W2 : W3;
        __hip_bfloat16* Wt = z == 0 ? T0 : z == 1 ? T1 : z == 2 ? T2 : T3;
        __shared__ float t[32][33];
        const int tx = tid & 31, ty = tid >> 5;
        const int n0 = (blockIdx.x & 31) * 32, k0 = (blockIdx.x >> 5) * 32;
#pragma unroll
        for (int r = 0; r < 4; r++)
            t[ty * 4 + r][tx] = W[(size_t)(k0 + ty * 4 + r) * EMBED + n0 + tx];
        __syncthreads();
#pragma unroll
        for (int r = 0; r < 4; r++)
            Wt[(size_t)(n0 + ty * 4 + r) * EMBED + k0 + tx] = __float2bfloat16(t[tx][ty * 4 + r]);
    }
}

// ---------------- 128x128 GEMM accumulate body (BK=32, B^T layout, K=1024) ----------------
__device__ __forceinline__ void gemm128_acc(
    const __hip_bfloat16* __restrict__ A, const __hip_bfloat16* __restrict__ Bt,
    int m0, int n0, __hip_bfloat16* As, __hip_bfloat16* Bs, f32x4 acc[4][4]) {
    const int K = EMBED;
    const int tid = threadIdx.x;
    const int wave = __builtin_amdgcn_readfirstlane(tid >> 6);
    const int lane = tid & 63, l15 = lane & 15, quad = lane >> 4;
    const int wm = (wave >> 1) * 64, wn = (wave & 1) * 64;
    const int srow = tid >> 2, sseg = (tid & 3) * 8;
    for (int k0 = 0; k0 < K; k0 += 32) {
        __syncthreads();
#pragma unroll
        for (int s = 0; s < 2; s++) {
            async_load16(A + (size_t)(m0 + s * 64 + srow) * K + k0 + sseg,
                         As + (size_t)(s * 256 + wave * 64) * 8);
            async_load16(Bt + (size_t)(n0 + s * 64 + srow) * K + k0 + sseg,
                         Bs + (size_t)(s * 256 + wave * 64) * 8);
        }
        __syncthreads();
        short8 af[4], bf[4];
#pragma unroll
        for (int t = 0; t < 4; t++) {
            af[t] = *(const short8*)(As + (wm + t * 16 + l15) * 32 + quad * 8);
            bf[t] = *(const short8*)(Bs + (wn + t * 16 + l15) * 32 + quad * 8);
        }
#pragma unroll
        for (int mt = 0; mt < 4; mt++)
#pragma unroll
            for (int nt = 0; nt < 4; nt++)
                acc[mt][nt] = __builtin_amdgcn_mfma_f32_16x16x32_bf16(af[mt], bf[nt], acc[mt][nt], 0, 0, 0);
    }
}

// ---------------- fused Q + K + V projections (V^T via LDS bounce, Q pre-scaled) ----------------
__global__ __launch_bounds__(256, 3) void proj128(
    const __hip_bfloat16* __restrict__ qbf, const __hip_bfloat16* __restrict__ cbf,
    const __hip_bfloat16* __restrict__ Wqt, const __hip_bfloat16* __restrict__ Wkvt,
    const float* __restrict__ bq, const float* __restrict__ bk, const float* __restrict__ bv,
    __hip_bfloat16* __restrict__ Qp, __hip_bfloat16* __restrict__ Kp, __hip_bfloat16* __restrict__ Vtr) {
    __shared__ __hip_bfloat16 smem[8704];  // As(4096) + Bs(4096); reused as T[64][136]
    __hip_bfloat16* As = smem;
    __hip_bfloat16* Bs = smem + 4096;
    const int j = blockIdx.x;
    const int blk = (j & 7) * 96 + (j >> 3);   // XCD swizzle
    const __hip_bfloat16 *A, *Bt;
    int m0, n0;
    if (blk < 256) {
        A = qbf; Bt = Wqt; m0 = (blk >> 3) * 128; n0 = (blk & 7) * 128;
    } else {
        const int f = blk - 256;
        A = cbf; Bt = Wkvt; m0 = (f >> 4) * 128; n0 = (f & 15) * 128;
    }
    f32x4 acc[4][4] = {};
    gemm128_acc(A, Bt, m0, n0, As, Bs, acc);

    const int tid = threadIdx.x;
    const int wave = __builtin_amdgcn_readfirstlane(tid >> 6);
    const int lane = tid & 63, l15 = lane & 15, quad = lane >> 4;
    const int wm = (wave >> 1) * 64, wn = (wave & 1) * 64;

    if (blk >= 256 && n0 >= 1024) {
        // V block: transpose 128x128 via LDS (two 64-col halves), coalesced writes
        const int cb = n0 - 1024;
        const int b2 = m0 >> 11;
        const int tokb = m0 & 2047;
        __hip_bfloat16* T = smem;  // 64 x 136
#pragma unroll
        for (int hh = 0; hh < 2; hh++) {
            __syncthreads();
            if ((wn >> 6) == hh) {
#pragma unroll
                for (int nt = 0; nt < 4; nt++) {
                    const int cn = nt * 16 + l15;
                    const float bvv = bv[cb + hh * 64 + cn];
#pragma unroll
                    for (int mt = 0; mt < 4; mt++) {
                        const int m = wm + mt * 16 + quad * 4;
                        __hip_bfloat16 vb[4];
#pragma unroll
                        for (int r = 0; r < 4; r++) vb[r] = __float2bfloat16(acc[mt][nt][r] + bvv);
                        *(ushort4*)(T + cn * 136 + m) = *(const ushort4*)vb;
                    }
                }
            }
            __syncthreads();
            const int r = tid >> 2;
            const int seg = (tid & 3) * 32;
            unsigned short* dst = (unsigned short*)Vtr +
                (size_t)(b2 * 1024 + cb + hh * 64 + r) * CLEN + tokb + seg;
            const unsigned short* srcp = (const unsigned short*)(T + r * 136 + seg);
#pragma unroll
            for (int u = 0; u < 4; u++)
                *(ushort8v*)(dst + u * 8) = *(const ushort8v*)(srcp + u * 8);
        }
    } else {
        const bool isQ = (blk < 256);
        const float* bias = isQ ? bq : bk;
        __hip_bfloat16* C = isQ ? Qp : Kp;
        const float sc = isQ ? QSCALE : 1.0f;
#pragma unroll
        for (int mt = 0; mt < 4; mt++) {
#pragma unroll
            for (int nt = 0; nt < 4; nt++) {
                const int c = n0 + wn + nt * 16 + l15;
                const float bvv = bias[c];
                const int r0 = m0 + wm + mt * 16 + quad * 4;
#pragma unroll
                for (int r = 0; r < 4; r++)
                    C[(size_t)(r0 + r) * 1024 + c] = __float2bfloat16((acc[mt][nt][r] + bvv) * sc);
            }
        }
    }
}

// ---------------- output projection: 64x128 tiles, fp32 out, XCD swizzle ----------------
__global__ __launch_bounds__(256, 4) void oproj(
    const __hip_bfloat16* __restrict__ A, const __hip_bfloat16* __restrict__ Bt,
    const float* __restrict__ bias, float* __restrict__ C) {
    __shared__ __hip_bfloat16 As[64 * 32];
    __shared__ __hip_bfloat16 Bs[128 * 32];
    const int K = EMBED, N = EMBED;
    const int j = blockIdx.x;
    const int L = (j & 7) * 64 + (j >> 3);
    const int m0 = (L >> 3) * 64, n0 = (L & 7) * 128;
    const int tid = threadIdx.x;
    const int wave = __builtin_amdgcn_readfirstlane(tid >> 6);
    const int lane = tid & 63, l15 = lane & 15, quad = lane >> 4;
    const int wm = (wave & 1) * 32, wn = (wave >> 1) * 64;
    const int srow = tid >> 2, sseg = (tid & 3) * 8;
    f32x4 acc[2][4] = {};
    for (int k0 = 0; k0 < K; k0 += 32) {
        __syncthreads();
        async_load16(A + (size_t)(m0 + srow) * K + k0 + sseg, As + (size_t)(wave * 64) * 8);
#pragma unroll
        for (int s = 0; s < 2; s++)
            async_load16(Bt + (size_t)(n0 + s * 64 + srow) * K + k0 + sseg,
                         Bs + (size_t)(s * 256 + wave * 64) * 8);
        __syncthreads();
        short8 af[2], bf[4];
#pragma unroll
        for (int t = 0; t < 2; t++)
            af[t] = *(const short8*)(As + (wm + t * 16 + l15) * 32 + quad * 8);
#pragma unroll
        for (int t = 0; t < 4; t++)
            bf[t] = *(const short8*)(Bs + (wn + t * 16 + l15) * 32 + quad * 8);
#pragma unroll
        for (int mt = 0; mt < 2; mt++)
#pragma unroll
            for (int nt = 0; nt < 4; nt++)
                acc[mt][nt] = __builtin_amdgcn_mfma_f32_16x16x32_bf16(af[mt], bf[nt], acc[mt][nt], 0, 0, 0);
    }
#pragma unroll
    for (int mt = 0; mt < 2; mt++) {
#pragma unroll
        for (int nt = 0; nt < 4; nt++) {
            const int c = n0 + wn + nt * 16 + l15;
            const float bvv = bias[c];
            const int r0 = m0 + wm + mt * 16 + quad * 4;
#pragma unroll
            for (int r = 0; r < 4; r++)
                C[(size_t)(r0 + r) * N + c] = acc[mt][nt][r] + bvv;
        }
    }
}

// ---------------- flash attention: 32x32x16 MFMA, S^T form, c-split x2 ----------------
// Conflict-free LDS swizzle: phys granule = logical ^ (row&7) ^ (row>>3).
// lsum on VALU (co-issues behind MFMA; R9 showed matrix pipe is the critical one).
__global__ __launch_bounds__(256, 4) void flash_attn(
    const __hip_bfloat16* __restrict__ Q, const __hip_bfloat16* __restrict__ K,
    const __hip_bfloat16* __restrict__ Vt, __hip_bfloat16* __restrict__ O) {
    __shared__ __hip_bfloat16 Ks[2][64 * 64];
    __shared__ __hip_bfloat16 Vs[2][64 * 64];
    const int tid = threadIdx.x;
    const int wave = __builtin_amdgcn_readfirstlane(tid >> 6);
    const int wq = wave & 1, wc = wave >> 1;
    const int lane = tid & 63, l31 = lane & 31, hbit = lane >> 5;
    const int j = blockIdx.x;
    const int L = (j & 7) * 128 + (j >> 3);  // XCD swizzle: 4 heads per XCD
    const int hy = L >> 5;
    const int b = hy >> 4, h = hy & 15;
    const int q0 = (L & 31) * 64;
    const size_t kbase = (size_t)b * CLEN * EMBED + (size_t)h * HD;
    const size_t vtbase = (size_t)((b * NH + h) * HD) * CLEN;
    const int srow8 = lane >> 3;               // 0..7
    const int sgb = (lane & 7) ^ srow8;        // swizzle base; per-issue: sgb ^ i
    __hip_bfloat16* stK = Ks[wc];
    __hip_bfloat16* stV = Vs[wc];

    const __hip_bfloat16* qptr =
        Q + (size_t)(b * QLEN + q0 + wq * 32 + l31) * EMBED + h * HD + hbit * 8;
    short8 qf[4];
#pragma unroll
    for (int t = 0; t < 4; t++) qf[t] = *(const short8*)(qptr + t * 16);

    f32x16 o[2] = {};
    float lsum = 0.f;
    const int cbase = wc * (CLEN / 2);

    for (int t = 0; t < 16; ++t) {
        const int c0 = cbase + t * 64;
        __syncthreads();
        if (wq == 0) {
#pragma unroll
            for (int i = 0; i < 8; i++)
                async_load16(K + kbase + (size_t)(c0 + i * 8 + srow8) * EMBED + (sgb ^ i) * 8,
                             stK + i * 512);
        } else {
#pragma unroll
            for (int i = 0; i < 8; i++)
                async_load16(Vt + vtbase + (size_t)(i * 8 + srow8) * CLEN + c0 + (sgb ^ i) * 8,
                             stV + i * 512);
        }
        __syncthreads();

#pragma unroll
        for (int mc = 0; mc < 2; mc++) {
            const int row = mc * 32 + l31;
            const int rsw = (row & 7) ^ (row >> 3);
            const __hip_bfloat16* kr = stK + row * 64;
            f32x16 s = {};
#pragma unroll
            for (int kc = 0; kc < 4; kc++) {
                short8 kf = *(const short8*)(kr + ((2 * kc + hbit) ^ rsw) * 8);
                s = __builtin_amdgcn_mfma_f32_32x32x16_bf16(kf, qf[kc], s, 0, 0, 0);
            }
            uint32_t dw[8];
#pragma unroll
            for (int i = 0; i < 8; i++) {
                const float p0 = __builtin_amdgcn_exp2f(s[2 * i]);
                const float p1 = __builtin_amdgcn_exp2f(s[2 * i + 1]);
                lsum += p0 + p1;
                dw[i] = pack2(p0, p1);
            }
#pragma unroll
            for (int tp = 0; tp < 2; tp++) {
                u32x4 fb;
#if __has_builtin(__builtin_amdgcn_permlane32_swap)
                {
                    auto s02 = __builtin_amdgcn_permlane32_swap(dw[4 * tp + 0], dw[4 * tp + 2], false, false);
                    auto s13 = __builtin_amdgcn_permlane32_swap(dw[4 * tp + 1], dw[4 * tp + 3], false, false);
                    fb[0] = s02[0];
                    fb[1] = s13[0];
                    fb[2] = s02[1];
                    fb[3] = s13[1];
                }
#else
                {
                    const uint32_t a0 = hbit ? dw[4 * tp + 2] : dw[4 * tp + 0];
                    const uint32_t a1 = hbit ? dw[4 * tp + 3] : dw[4 * tp + 1];
                    const uint32_t b0 = hbit ? dw[4 * tp + 0] : dw[4 * tp + 2];
                    const uint32_t b1 = hbit ? dw[4 * tp + 1] : dw[4 * tp + 3];
                    const uint32_t x0 = (uint32_t)__shfl_xor((int)b0, 32);
                    const uint32_t x1 = (uint32_t)__shfl_xor((int)b1, 32);
                    fb[0] = hbit ? x0 : a0;
                    fb[1] = hbit ? x1 : a1;
                    fb[2] = hbit ? a0 : x0;
                    fb[3] = hbit ? a1 : x1;
                }
#endif
                const short8 pfr = __builtin_bit_cast(short8, fb);
                const int kc2 = mc * 2 + tp;
#pragma unroll
                for (int dm = 0; dm < 2; dm++) {
                    const int vrow = dm * 32 + l31;
                    const int vsw = (vrow & 7) ^ (vrow >> 3);
                    short8 vf = *(const short8*)(stV + vrow * 64 + ((2 * kc2 + hbit) ^ vsw) * 8);
                    o[dm] = __builtin_amdgcn_mfma_f32_32x32x16_bf16(vf, pfr, o[dm], 0, 0, 0);
                }
            }
        }
    }

    // ---- combine c-halves (additive), then normalize & store ----
    __syncthreads();
    float4* scr4 = (float4*)&Ks[0][0];
    float* scrl = (float*)&Vs[0][0];
    if (wc == 1) {
#pragma unroll
        for (int i = 0; i < 8; i++) {
            float4 c4;
            c4.x = o[i >> 2][(i & 3) * 4 + 0];
            c4.y = o[i >> 2][(i & 3) * 4 + 1];
            c4.z = o[i >> 2][(i & 3) * 4 + 2];
            c4.w = o[i >> 2][(i & 3) * 4 + 3];
            scr4[i * 128 + wq * 64 + lane] = c4;
        }
        scrl[wq * 64 + lane] = lsum;
    }
    __syncthreads();
    if (wc == 0) {
        lsum += scrl[wq * 64 + lane];
#pragma unroll
        for (int i = 0; i < 8; i++) {
            float4 p = scr4[i * 128 + wq * 64 + lane];
            o[i >> 2][(i & 3) * 4 + 0] += p.x;
            o[i >> 2][(i & 3) * 4 + 1] += p.y;
            o[i >> 2][(i & 3) * 4 + 2] += p.z;
            o[i >> 2][(i & 3) * 4 + 3] += p.w;
        }
        lsum += __shfl_xor(lsum, 32);
        const float inv = 1.0f / lsum;
        const int q = q0 + wq * 32 + l31;
        __hip_bfloat16* orow = O + (size_t)(b * QLEN + q) * EMBED + h * HD;
#pragma unroll
        for (int dm = 0; dm < 2; dm++) {
#pragma unroll
            for (int g = 0; g < 4; g++) {
                __hip_bfloat16 ob[4];
#pragma unroll
                for (int r = 0; r < 4; r++) ob[r] = __float2bfloat16(o[dm][g * 4 + r] * inv);
                *(ushort4*)(orow + dm * 32 + hbit * 4 + g * 8) = *(const ushort4*)ob;
            }
        }
    }
}

extern "C" void kernel_launch(void* const* d_in, const int* in_sizes, int n_in,
                              void* d_out, int out_size, void* d_ws, size_t ws_size,
                              hipStream_t stream) {
    const float* query = (const float*)d_in[0];
    const float* context = (const float*)d_in[1];
    const float* Wq = (const float*)d_in[2];
    const float* bq = (const float*)d_in[3];
    const float* Wk = (const float*)d_in[4];
    const float* bk = (const float*)d_in[5];
    const float* Wv = (const float*)d_in[6];
    const float* bv = (const float*)d_in[7];
    const float* Wo = (const float*)d_in[8];
    const float* bo = (const float*)d_in[9];
    float* out = (float*)d_out;

    const int NTOK = BATCH * QLEN;   // 4096
    const int NACT = NTOK * EMBED;   // 4,194,304
    const int NW = EMBED * EMBED;    // 1,048,576

    __hip_bfloat16* qbf = (__hip_bfloat16*)d_ws;
    __hip_bfloat16* cbf = qbf + NACT;
    __hip_bfloat16* Wqt = cbf + NACT;
    __hip_bfloat16* Wkt = Wqt + NW;
    __hip_bfloat16* Wvt = Wkt + NW;
    __hip_bfloat16* Wot = Wvt + NW;
    __hip_bfloat16* Qp = Wot + NW;
    __hip_bfloat16* Kp = Qp + NACT;
    __hip_bfloat16* Vtr = Kp + NACT;
    __hip_bfloat16* att = Vtr + NACT;

    prep<<<dim3(1024, 6), 256, 0, stream>>>(query, context, qbf, cbf,
                                            Wq, Wk, Wv, Wo, Wqt, Wkt, Wvt, Wot);

    proj128<<<768, 256, 0, stream>>>(qbf, cbf, Wqt, Wkt, bq, bk, bv, Qp, Kp, Vtr);

    flash_attn<<<1024, 256, 0, stream>>>(Qp, Kp, Vtr, att);

    oproj<<<512, 256, 0, stream>>>(att, Wot, bo, out);
}